// Round 1
// baseline (308.700 us; speedup 1.0000x reference)
//
#include <hip/hip_runtime.h>
#include <hip/hip_bf16.h>

#define N_NODES 50000
#define N_EDGES 800000
#define DFEAT 96

// ---------------- degree count ----------------
__global__ __launch_bounds__(256) void degree_kernel(
    const int* __restrict__ src, const int* __restrict__ dst,
    int* __restrict__ deg_out, int* __restrict__ deg_in, int nedges) {
    int e = blockIdx.x * 256 + threadIdx.x;
    if (e >= nedges) return;
    atomicAdd(&deg_out[src[e]], 1);
    atomicAdd(&deg_in[dst[e]], 1);
}

// ---------------- single-block exclusive scan ----------------
__global__ __launch_bounds__(1024) void scan_kernel(
    const int* __restrict__ deg, int* __restrict__ offs, int n) {
    __shared__ int wsum[16];
    __shared__ int chunk_total;
    int tid = threadIdx.x;
    int lane = tid & 63, wave = tid >> 6;
    int carry = 0;
    for (int base = 0; base < n; base += 1024) {
        int i = base + tid;
        int v = (i < n) ? deg[i] : 0;
        // inclusive wave scan
        int x = v;
        #pragma unroll
        for (int off = 1; off < 64; off <<= 1) {
            int t = __shfl_up(x, off, 64);
            if (lane >= off) x += t;
        }
        if (lane == 63) wsum[wave] = x;
        __syncthreads();
        if (wave == 0) {
            int s = (lane < 16) ? wsum[lane] : 0;
            int y = s;
            #pragma unroll
            for (int off = 1; off < 16; off <<= 1) {
                int t = __shfl_up(y, off, 64);
                if (lane >= off) y += t;
            }
            if (lane < 16) wsum[lane] = y - s;   // exclusive wave prefix
            if (lane == 15) chunk_total = y;     // inclusive total of chunk
        }
        __syncthreads();
        if (i < n) offs[i] = carry + wsum[wave] + (x - v);
        carry += chunk_total;
        __syncthreads();  // protect wsum/chunk_total before next iteration
    }
    if (tid == 0) offs[n] = carry;
}

// ---------------- CSR fill (counting sort by dst) ----------------
__global__ __launch_bounds__(256) void fill_kernel(
    const int* __restrict__ src, const int* __restrict__ dst,
    const int* __restrict__ offs, int* __restrict__ cursor,
    int* __restrict__ csr_src, int nedges) {
    int e = blockIdx.x * 256 + threadIdx.x;
    if (e >= nedges) return;
    int d = dst[e];
    int p = atomicAdd(&cursor[d], 1);
    csr_src[offs[d] + p] = src[e];
}

// ---------------- GEMM: h = (x @ W) * inv_sqrt(deg_out[row]) ----------------
#define GROWS 32
__global__ __launch_bounds__(256) void gemm_kernel(
    const float* __restrict__ x, const float* __restrict__ W,
    const int* __restrict__ deg_out, float* __restrict__ h, int nrows) {
    __shared__ float4 w4[96 * 24];       // 36 KB, w4[k*24 + jq]
    __shared__ float  xl[GROWS * 100];   // 12.5 KB, padded stride 100 (16B-aligned, bank-spread)
    int tid = threadIdx.x;

    // stage W (contiguous row-major copy matches w4 layout)
    const float4* Wv = (const float4*)W;
    for (int i = tid; i < 2304; i += 256) w4[i] = Wv[i];

    // stage x tile rows [r0, r0+32)
    int r0 = blockIdx.x * GROWS;
    int nvalid = nrows - r0; if (nvalid > GROWS) nvalid = GROWS;
    const float4* xv = (const float4*)(x + (size_t)r0 * DFEAT);
    int n4 = nvalid * 24;
    for (int i = tid; i < n4; i += 256) {
        int r = i / 24, c = i - r * 24;
        *(float4*)&xl[r * 100 + c * 4] = xv[i];
    }
    __syncthreads();

    int rl = tid >> 3;             // row 0..31
    int jq = (tid & 7) * 3;        // float4-column base (3 quads = 12 cols)
    float4 a0 = {0,0,0,0}, a1 = {0,0,0,0}, a2 = {0,0,0,0};
    #pragma unroll 8
    for (int k = 0; k < 96; ++k) {
        float xs = xl[rl * 100 + k];
        float4 w0 = w4[k * 24 + jq];
        float4 w1 = w4[k * 24 + jq + 1];
        float4 w2 = w4[k * 24 + jq + 2];
        a0.x += xs * w0.x; a0.y += xs * w0.y; a0.z += xs * w0.z; a0.w += xs * w0.w;
        a1.x += xs * w1.x; a1.y += xs * w1.y; a1.z += xs * w1.z; a1.w += xs * w1.w;
        a2.x += xs * w2.x; a2.y += xs * w2.y; a2.z += xs * w2.z; a2.w += xs * w2.w;
    }
    int row = r0 + rl;
    if (row < nrows) {
        int d = deg_out[row];
        float s = (d > 0) ? rsqrtf((float)d) : 0.f;
        float4* hv = (float4*)(h + (size_t)row * DFEAT);
        a0.x *= s; a0.y *= s; a0.z *= s; a0.w *= s;
        a1.x *= s; a1.y *= s; a1.z *= s; a1.w *= s;
        a2.x *= s; a2.y *= s; a2.z *= s; a2.w *= s;
        hv[jq] = a0; hv[jq + 1] = a1; hv[jq + 2] = a2;
    }
}

// ---------------- aggregate: out[n] = inv_sqrt_in[n] * sum_{e in(n)} h[src_e] + b ----------------
__global__ __launch_bounds__(256) void agg_kernel(
    const float* __restrict__ h, const int* __restrict__ csr_src,
    const int* __restrict__ offs, const float* __restrict__ b,
    float* __restrict__ out, int nnodes) {
    int tid = threadIdx.x;
    int n = blockIdx.x * 32 + (tid >> 3);
    if (n >= nnodes) return;
    int fq = tid & 7;                     // this lane owns float4 slots fq, fq+8, fq+16
    int start = offs[n], end = offs[n + 1];
    float4 a0 = {0,0,0,0}, a1 = {0,0,0,0}, a2 = {0,0,0,0};
    const float4* hb = (const float4*)h;  // row stride 24 float4
    for (int e = start; e < end; ++e) {
        int s = csr_src[e];
        const float4* row = hb + (size_t)s * 24;
        float4 v0 = row[fq], v1 = row[fq + 8], v2 = row[fq + 16];
        a0.x += v0.x; a0.y += v0.y; a0.z += v0.z; a0.w += v0.w;
        a1.x += v1.x; a1.y += v1.y; a1.z += v1.z; a1.w += v1.w;
        a2.x += v2.x; a2.y += v2.y; a2.z += v2.z; a2.w += v2.w;
    }
    float inv = (end > start) ? rsqrtf((float)(end - start)) : 0.f;
    const float4* b4 = (const float4*)b;
    float4 bb0 = b4[fq], bb1 = b4[fq + 8], bb2 = b4[fq + 16];
    float4* o = (float4*)(out + (size_t)n * DFEAT);
    float4 r0, r1, r2;
    r0.x = a0.x * inv + bb0.x; r0.y = a0.y * inv + bb0.y; r0.z = a0.z * inv + bb0.z; r0.w = a0.w * inv + bb0.w;
    r1.x = a1.x * inv + bb1.x; r1.y = a1.y * inv + bb1.y; r1.z = a1.z * inv + bb1.z; r1.w = a1.w * inv + bb1.w;
    r2.x = a2.x * inv + bb2.x; r2.y = a2.y * inv + bb2.y; r2.z = a2.z * inv + bb2.z; r2.w = a2.w * inv + bb2.w;
    o[fq] = r0; o[fq + 8] = r1; o[fq + 16] = r2;
}

extern "C" void kernel_launch(void* const* d_in, const int* in_sizes, int n_in,
                              void* d_out, int out_size, void* d_ws, size_t ws_size,
                              hipStream_t stream) {
    const float* x  = (const float*)d_in[0];
    const float* W  = (const float*)d_in[1];
    const float* b  = (const float*)d_in[2];
    const int*   src = (const int*)d_in[3];
    const int*   dst = (const int*)d_in[4];
    float* out = (float*)d_out;

    // workspace layout
    int* deg_out = (int*)d_ws;                 // 50000
    int* deg_in  = deg_out + N_NODES;          // 50000
    int* cursor  = deg_in + N_NODES;           // 50000
    int* offs    = cursor + N_NODES;           // 50001
    int* csr_src = offs + N_NODES + 1;         // 800000
    size_t h_off = ((size_t)(3 * N_NODES + N_NODES + 1 + N_EDGES) * 4 + 15) & ~(size_t)15;
    float* h = (float*)((char*)d_ws + h_off);  // 50000*96 floats

    // zero deg_out, deg_in, cursor (contiguous)
    hipMemsetAsync(d_ws, 0, (size_t)3 * N_NODES * 4, stream);

    int eblocks = (N_EDGES + 255) / 256;
    degree_kernel<<<eblocks, 256, 0, stream>>>(src, dst, deg_out, deg_in, N_EDGES);
    scan_kernel<<<1, 1024, 0, stream>>>(deg_in, offs, N_NODES);
    fill_kernel<<<eblocks, 256, 0, stream>>>(src, dst, offs, cursor, csr_src, N_EDGES);

    int gblocks = (N_NODES + GROWS - 1) / GROWS;
    gemm_kernel<<<gblocks, 256, 0, stream>>>(x, W, deg_out, h, N_NODES);

    int ablocks = (N_NODES + 31) / 32;
    agg_kernel<<<ablocks, 256, 0, stream>>>(h, csr_src, offs, b, out, N_NODES);
}

// Round 2
// 228.371 us; speedup vs baseline: 1.3517x; 1.3517x over previous
//
#include <hip/hip_runtime.h>

#define N_NODES 50000
#define N_EDGES 800000
#define DFEAT 96

// ---- degrees via range-partitioned LDS histograms (zero global atomics) ----
#define NRANGE 13
#define NCHUNK 20
#define RBITS  12
#define RSIZE  4096
#define CHUNK_E (N_EDGES / NCHUNK)   // 40000

__global__ __launch_bounds__(256) void deg_hist_kernel(
    const int* __restrict__ src, const int* __restrict__ dst,
    int* __restrict__ pout, int* __restrict__ pin) {
    __shared__ int hout[RSIZE];
    __shared__ int hin[RSIZE];
    int tid = threadIdx.x;
    int r = blockIdx.x % NRANGE;
    int c = blockIdx.x / NRANGE;
    for (int i = tid; i < RSIZE; i += 256) { hout[i] = 0; hin[i] = 0; }
    __syncthreads();
    int lo = r << RBITS;
    const int4* s4 = (const int4*)(src + c * CHUNK_E);
    const int4* d4 = (const int4*)(dst + c * CHUNK_E);
    const int n4 = CHUNK_E / 4;  // 10000
    for (int i = tid; i < n4; i += 256) {
        int4 s = s4[i];
        int4 d = d4[i];
        unsigned a;
        a = (unsigned)(s.x - lo); if (a < RSIZE) atomicAdd(&hout[a], 1);
        a = (unsigned)(s.y - lo); if (a < RSIZE) atomicAdd(&hout[a], 1);
        a = (unsigned)(s.z - lo); if (a < RSIZE) atomicAdd(&hout[a], 1);
        a = (unsigned)(s.w - lo); if (a < RSIZE) atomicAdd(&hout[a], 1);
        a = (unsigned)(d.x - lo); if (a < RSIZE) atomicAdd(&hin[a], 1);
        a = (unsigned)(d.y - lo); if (a < RSIZE) atomicAdd(&hin[a], 1);
        a = (unsigned)(d.z - lo); if (a < RSIZE) atomicAdd(&hin[a], 1);
        a = (unsigned)(d.w - lo); if (a < RSIZE) atomicAdd(&hin[a], 1);
    }
    __syncthreads();
    int base = (r * NCHUNK + c) << RBITS;
    for (int i = tid; i < RSIZE; i += 256) {
        pout[base + i] = hout[i];   // coalesced, non-atomic flush
        pin[base + i]  = hin[i];
    }
}

__global__ __launch_bounds__(256) void deg_reduce_kernel(
    const int* __restrict__ pout, const int* __restrict__ pin,
    int* __restrict__ deg_out, int* __restrict__ deg_in) {
    int n = blockIdx.x * 256 + threadIdx.x;
    if (n >= N_NODES) return;
    int r = n >> RBITS, b = n & (RSIZE - 1);
    const int* po = pout + ((size_t)r * NCHUNK << RBITS) + b;
    const int* pi = pin  + ((size_t)r * NCHUNK << RBITS) + b;
    int so = 0, si = 0;
    #pragma unroll
    for (int c = 0; c < NCHUNK; ++c) { so += po[c << RBITS]; si += pi[c << RBITS]; }
    deg_out[n] = so;
    deg_in[n]  = si;
}

// ---- hierarchical exclusive scan of deg_in -> offs ----
__global__ __launch_bounds__(256) void scan_bsum_kernel(
    const int* __restrict__ deg, int* __restrict__ bsum) {
    __shared__ int ws[4];
    int tid = threadIdx.x;
    int i = blockIdx.x * 256 + tid;
    int v = (i < N_NODES) ? deg[i] : 0;
    #pragma unroll
    for (int off = 32; off; off >>= 1) v += __shfl_down(v, off, 64);
    if ((tid & 63) == 0) ws[tid >> 6] = v;
    __syncthreads();
    if (tid == 0) bsum[blockIdx.x] = ws[0] + ws[1] + ws[2] + ws[3];
}

__global__ __launch_bounds__(256) void scan_base_kernel(
    const int* __restrict__ bsum, int* __restrict__ bbase,
    int* __restrict__ offs, int nb) {
    __shared__ int wsum[4];
    int tid = threadIdx.x, lane = tid & 63, wave = tid >> 6;
    int v = (tid < nb) ? bsum[tid] : 0;
    int x = v;
    #pragma unroll
    for (int off = 1; off < 64; off <<= 1) {
        int t = __shfl_up(x, off, 64);
        if (lane >= off) x += t;
    }
    if (lane == 63) wsum[wave] = x;
    __syncthreads();
    int wb = 0;
    for (int w = 0; w < wave; ++w) wb += wsum[w];
    if (tid < nb) bbase[tid] = wb + x - v;
    if (tid == 0) offs[N_NODES] = wsum[0] + wsum[1] + wsum[2] + wsum[3];
}

__global__ __launch_bounds__(256) void scan_final_kernel(
    const int* __restrict__ deg, const int* __restrict__ bbase,
    int* __restrict__ offs) {
    __shared__ int wsum[4];
    int tid = threadIdx.x, lane = tid & 63, wave = tid >> 6;
    int i = blockIdx.x * 256 + tid;
    int v = (i < N_NODES) ? deg[i] : 0;
    int x = v;
    #pragma unroll
    for (int off = 1; off < 64; off <<= 1) {
        int t = __shfl_up(x, off, 64);
        if (lane >= off) x += t;
    }
    if (lane == 63) wsum[wave] = x;
    __syncthreads();
    int wb = 0;
    for (int w = 0; w < wave; ++w) wb += wsum[w];
    if (i < N_NODES) offs[i] = bbase[blockIdx.x] + wb + x - v;
}

// ---- CSR fill (counting sort by dst) ----
__global__ __launch_bounds__(256) void fill_kernel(
    const int* __restrict__ src, const int* __restrict__ dst,
    const int* __restrict__ offs, int* __restrict__ cursor,
    int* __restrict__ csr_src, int nedges) {
    int e = blockIdx.x * 256 + threadIdx.x;
    if (e >= nedges) return;
    int d = dst[e];
    int p = atomicAdd(&cursor[d], 1);
    csr_src[offs[d] + p] = src[e];
}

// ---- GEMM: h = (x @ W) * inv_sqrt(deg_out[row]) ----
// 512 threads, 256 rows/block, thread = 4 rows x 12 cols.
// xT staged transposed (xT[col][row]) -> conflict-free b128 reads of 4 rows.
#define GR 256
__global__ __launch_bounds__(512) void gemm_kernel(
    const float* __restrict__ x, const float* __restrict__ W,
    const int* __restrict__ deg_out, float* __restrict__ h, int nrows) {
    __shared__ float ws[96 * 96];    // W row-major [k][j], 36 KB
    __shared__ float xT[96 * GR];    // xT[col][row], 96 KB  (total 132 KB -> 1 block/CU)
    int tid = threadIdx.x;

    const float4* Wv = (const float4*)W;
    float4* wv = (float4*)ws;
    for (int i = tid; i < 2304; i += 512) wv[i] = Wv[i];

    int r0 = blockIdx.x * GR;
    int nvalid = nrows - r0; if (nvalid > GR) nvalid = GR;
    const float4* xv = (const float4*)x;
    // i = c4*GR + row : each lane walks its own row's quads (L1-resident lines),
    // LDS writes land row-consecutive -> 2-way (free) bank aliasing.
    for (int i = tid; i < 24 * GR; i += 512) {
        int row = i & (GR - 1);
        int c4 = i >> 8;
        if (row < nvalid) {
            float4 v = xv[(size_t)(r0 + row) * 24 + c4];
            xT[(c4 * 4 + 0) * GR + row] = v.x;
            xT[(c4 * 4 + 1) * GR + row] = v.y;
            xT[(c4 * 4 + 2) * GR + row] = v.z;
            xT[(c4 * 4 + 3) * GR + row] = v.w;
        }
    }
    __syncthreads();

    int rg = tid >> 3;            // 0..63 -> rows rg*4 .. rg*4+3
    int cg = tid & 7;             // cols 12*cg .. 12*cg+11
    float4 a0[4], a1[4], a2[4];
    #pragma unroll
    for (int r = 0; r < 4; ++r) { a0[r] = {0,0,0,0}; a1[r] = {0,0,0,0}; a2[r] = {0,0,0,0}; }

    #pragma unroll 4
    for (int k = 0; k < 96; ++k) {
        float4 xs = *(const float4*)&xT[k * GR + rg * 4];
        float4 w0 = *(const float4*)&ws[k * 96 + 12 * cg];
        float4 w1 = *(const float4*)&ws[k * 96 + 12 * cg + 4];
        float4 w2 = *(const float4*)&ws[k * 96 + 12 * cg + 8];
        float xr[4] = {xs.x, xs.y, xs.z, xs.w};
        #pragma unroll
        for (int r = 0; r < 4; ++r) {
            a0[r].x += xr[r] * w0.x; a0[r].y += xr[r] * w0.y; a0[r].z += xr[r] * w0.z; a0[r].w += xr[r] * w0.w;
            a1[r].x += xr[r] * w1.x; a1[r].y += xr[r] * w1.y; a1[r].z += xr[r] * w1.z; a1[r].w += xr[r] * w1.w;
            a2[r].x += xr[r] * w2.x; a2[r].y += xr[r] * w2.y; a2[r].z += xr[r] * w2.z; a2[r].w += xr[r] * w2.w;
        }
    }

    #pragma unroll
    for (int r = 0; r < 4; ++r) {
        int row = r0 + rg * 4 + r;
        if (row < nrows) {
            int d = deg_out[row];
            float s = (d > 0) ? rsqrtf((float)d) : 0.f;
            float4* hv = (float4*)(h + (size_t)row * DFEAT + 12 * cg);
            float4 o0 = a0[r], o1 = a1[r], o2 = a2[r];
            o0.x *= s; o0.y *= s; o0.z *= s; o0.w *= s;
            o1.x *= s; o1.y *= s; o1.z *= s; o1.w *= s;
            o2.x *= s; o2.y *= s; o2.z *= s; o2.w *= s;
            hv[0] = o0; hv[1] = o1; hv[2] = o2;
        }
    }
}

// ---- aggregate: out[n] = inv_sqrt_in[n] * sum h[src_e] + b ----
__global__ __launch_bounds__(256) void agg_kernel(
    const float* __restrict__ h, const int* __restrict__ csr_src,
    const int* __restrict__ offs, const float* __restrict__ b,
    float* __restrict__ out, int nnodes) {
    int tid = threadIdx.x;
    int n = blockIdx.x * 32 + (tid >> 3);
    if (n >= nnodes) return;
    int fq = tid & 7;
    int start = offs[n], end = offs[n + 1];
    float4 a0 = {0,0,0,0}, a1 = {0,0,0,0}, a2 = {0,0,0,0};
    const float4* hb = (const float4*)h;
    int e = start;
    for (; e + 2 <= end; e += 2) {
        const float4* r0 = hb + (size_t)csr_src[e] * 24;
        const float4* r1 = hb + (size_t)csr_src[e + 1] * 24;
        float4 v0 = r0[fq], v1 = r0[fq + 8], v2 = r0[fq + 16];
        float4 u0 = r1[fq], u1 = r1[fq + 8], u2 = r1[fq + 16];
        a0.x += v0.x; a0.y += v0.y; a0.z += v0.z; a0.w += v0.w;
        a1.x += v1.x; a1.y += v1.y; a1.z += v1.z; a1.w += v1.w;
        a2.x += v2.x; a2.y += v2.y; a2.z += v2.z; a2.w += v2.w;
        a0.x += u0.x; a0.y += u0.y; a0.z += u0.z; a0.w += u0.w;
        a1.x += u1.x; a1.y += u1.y; a1.z += u1.z; a1.w += u1.w;
        a2.x += u2.x; a2.y += u2.y; a2.z += u2.z; a2.w += u2.w;
    }
    if (e < end) {
        const float4* r0 = hb + (size_t)csr_src[e] * 24;
        float4 v0 = r0[fq], v1 = r0[fq + 8], v2 = r0[fq + 16];
        a0.x += v0.x; a0.y += v0.y; a0.z += v0.z; a0.w += v0.w;
        a1.x += v1.x; a1.y += v1.y; a1.z += v1.z; a1.w += v1.w;
        a2.x += v2.x; a2.y += v2.y; a2.z += v2.z; a2.w += v2.w;
    }
    float inv = (end > start) ? rsqrtf((float)(end - start)) : 0.f;
    const float4* b4 = (const float4*)b;
    float4 bb0 = b4[fq], bb1 = b4[fq + 8], bb2 = b4[fq + 16];
    float4* o = (float4*)(out + (size_t)n * DFEAT);
    float4 r0, r1, r2;
    r0.x = a0.x * inv + bb0.x; r0.y = a0.y * inv + bb0.y; r0.z = a0.z * inv + bb0.z; r0.w = a0.w * inv + bb0.w;
    r1.x = a1.x * inv + bb1.x; r1.y = a1.y * inv + bb1.y; r1.z = a1.z * inv + bb1.z; r1.w = a1.w * inv + bb1.w;
    r2.x = a2.x * inv + bb2.x; r2.y = a2.y * inv + bb2.y; r2.z = a2.z * inv + bb2.z; r2.w = a2.w * inv + bb2.w;
    o[fq] = r0; o[fq + 8] = r1; o[fq + 16] = r2;
}

extern "C" void kernel_launch(void* const* d_in, const int* in_sizes, int n_in,
                              void* d_out, int out_size, void* d_ws, size_t ws_size,
                              hipStream_t stream) {
    const float* x  = (const float*)d_in[0];
    const float* W  = (const float*)d_in[1];
    const float* b  = (const float*)d_in[2];
    const int*   src = (const int*)d_in[3];
    const int*   dst = (const int*)d_in[4];
    float* out = (float*)d_out;

    // workspace layout (ints)
    int* deg_out = (int*)d_ws;                   // 50000
    int* deg_in  = deg_out + N_NODES;            // 50000
    int* cursor  = deg_in + N_NODES;             // 50000
    int* offs    = cursor + N_NODES;             // 50001
    int* csr_src = offs + N_NODES + 1;           // 800000
    int* bsum    = csr_src + N_EDGES;            // 196
    int* bbase   = bsum + 196;                   // 196
    size_t h_off = (((size_t)(3 * N_NODES + N_NODES + 1 + N_EDGES + 392)) * 4 + 15) & ~(size_t)15;
    float* h = (float*)((char*)d_ws + h_off);    // 50000*96 floats (19.2 MB)
    // partials alias the h region (dead before gemm writes h)
    int* pout = (int*)h;                                     // 13*20*4096
    int* pin  = pout + ((size_t)NRANGE * NCHUNK << RBITS);   // 13*20*4096

    hipMemsetAsync(cursor, 0, (size_t)N_NODES * 4, stream);

    deg_hist_kernel<<<NRANGE * NCHUNK, 256, 0, stream>>>(src, dst, pout, pin);
    deg_reduce_kernel<<<(N_NODES + 255) / 256, 256, 0, stream>>>(pout, pin, deg_out, deg_in);

    int nb = (N_NODES + 255) / 256;  // 196
    scan_bsum_kernel<<<nb, 256, 0, stream>>>(deg_in, bsum);
    scan_base_kernel<<<1, 256, 0, stream>>>(bsum, bbase, offs, nb);
    scan_final_kernel<<<nb, 256, 0, stream>>>(deg_in, bbase, offs);

    fill_kernel<<<(N_EDGES + 255) / 256, 256, 0, stream>>>(src, dst, offs, cursor, csr_src, N_EDGES);

    gemm_kernel<<<(N_NODES + GR - 1) / GR, 512, 0, stream>>>(x, W, deg_out, h, N_NODES);

    agg_kernel<<<(N_NODES + 31) / 32, 256, 0, stream>>>(h, csr_src, offs, b, out, N_NODES);
}

// Round 3
// 189.012 us; speedup vs baseline: 1.6332x; 1.2082x over previous
//
#include <hip/hip_runtime.h>

#define N_NODES 50000
#define N_EDGES 800000
#define DFEAT 96

// range partitioning: 7 ranges x 8192 nodes; 40 edge chunks of 20000
#define RBITS  13
#define RSIZE  8192
#define NRANGE 7
#define NCHUNK 40
#define CHUNK_E (N_EDGES / NCHUNK)   // 20000

// ---- pass 1: per-(range,chunk) LDS histograms of src and dst ----
__global__ __launch_bounds__(256) void deg_hist_kernel(
    const int* __restrict__ src, const int* __restrict__ dst,
    int* __restrict__ pout, int* __restrict__ pin) {
    __shared__ int hout[RSIZE];
    __shared__ int hin[RSIZE];
    int tid = threadIdx.x;
    int r = blockIdx.x % NRANGE;
    int c = blockIdx.x / NRANGE;
    for (int i = tid; i < RSIZE; i += 256) { hout[i] = 0; hin[i] = 0; }
    __syncthreads();
    int lo = r << RBITS;
    const int4* s4 = (const int4*)(src + c * CHUNK_E);
    const int4* d4 = (const int4*)(dst + c * CHUNK_E);
    for (int i = tid; i < CHUNK_E / 4; i += 256) {
        int4 s = s4[i];
        int4 d = d4[i];
        unsigned a;
        a = (unsigned)(s.x - lo); if (a < RSIZE) atomicAdd(&hout[a], 1);
        a = (unsigned)(s.y - lo); if (a < RSIZE) atomicAdd(&hout[a], 1);
        a = (unsigned)(s.z - lo); if (a < RSIZE) atomicAdd(&hout[a], 1);
        a = (unsigned)(s.w - lo); if (a < RSIZE) atomicAdd(&hout[a], 1);
        a = (unsigned)(d.x - lo); if (a < RSIZE) atomicAdd(&hin[a], 1);
        a = (unsigned)(d.y - lo); if (a < RSIZE) atomicAdd(&hin[a], 1);
        a = (unsigned)(d.z - lo); if (a < RSIZE) atomicAdd(&hin[a], 1);
        a = (unsigned)(d.w - lo); if (a < RSIZE) atomicAdd(&hin[a], 1);
    }
    __syncthreads();
    size_t base = (size_t)(r * NCHUNK + c) << RBITS;
    for (int i = tid; i < RSIZE; i += 256) {
        pout[base + i] = hout[i];
        pin[base + i]  = hin[i];
    }
}

// ---- pass 2: reduce to degrees AND rewrite pin as per-chunk exclusive prefix ----
__global__ __launch_bounds__(256) void deg_reduce_kernel(
    const int* __restrict__ pout, int* __restrict__ pin,
    int* __restrict__ deg_out, int* __restrict__ deg_in) {
    int n = blockIdx.x * 256 + threadIdx.x;
    if (n >= N_NODES) return;
    int r = n >> RBITS, bb = n & (RSIZE - 1);
    size_t stride = (size_t)1 << RBITS;
    const int* po = pout + (((size_t)r * NCHUNK) << RBITS) + bb;
    int*       pi = pin  + (((size_t)r * NCHUNK) << RBITS) + bb;
    int so = 0, si = 0;
    #pragma unroll 8
    for (int c = 0; c < NCHUNK; ++c) {
        so += po[c * stride];
        int t = pi[c * stride];
        pi[c * stride] = si;   // exclusive prefix over chunks
        si += t;
    }
    deg_out[n] = so;
    deg_in[n]  = si;
}

// ---- hierarchical exclusive scan of deg_in -> offs ----
__global__ __launch_bounds__(256) void scan_bsum_kernel(
    const int* __restrict__ deg, int* __restrict__ bsum) {
    __shared__ int ws[4];
    int tid = threadIdx.x;
    int i = blockIdx.x * 256 + tid;
    int v = (i < N_NODES) ? deg[i] : 0;
    #pragma unroll
    for (int off = 32; off; off >>= 1) v += __shfl_down(v, off, 64);
    if ((tid & 63) == 0) ws[tid >> 6] = v;
    __syncthreads();
    if (tid == 0) bsum[blockIdx.x] = ws[0] + ws[1] + ws[2] + ws[3];
}

__global__ __launch_bounds__(256) void scan_base_kernel(
    const int* __restrict__ bsum, int* __restrict__ bbase,
    int* __restrict__ offs, int nb) {
    __shared__ int wsum[4];
    int tid = threadIdx.x, lane = tid & 63, wave = tid >> 6;
    int v = (tid < nb) ? bsum[tid] : 0;
    int x = v;
    #pragma unroll
    for (int off = 1; off < 64; off <<= 1) {
        int t = __shfl_up(x, off, 64);
        if (lane >= off) x += t;
    }
    if (lane == 63) wsum[wave] = x;
    __syncthreads();
    int wb = 0;
    for (int w = 0; w < wave; ++w) wb += wsum[w];
    if (tid < nb) bbase[tid] = wb + x - v;
    if (tid == 0) offs[N_NODES] = wsum[0] + wsum[1] + wsum[2] + wsum[3];
}

__global__ __launch_bounds__(256) void scan_final_kernel(
    const int* __restrict__ deg, const int* __restrict__ bbase,
    int* __restrict__ offs) {
    __shared__ int wsum[4];
    int tid = threadIdx.x, lane = tid & 63, wave = tid >> 6;
    int i = blockIdx.x * 256 + tid;
    int v = (i < N_NODES) ? deg[i] : 0;
    int x = v;
    #pragma unroll
    for (int off = 1; off < 64; off <<= 1) {
        int t = __shfl_up(x, off, 64);
        if (lane >= off) x += t;
    }
    if (lane == 63) wsum[wave] = x;
    __syncthreads();
    int wb = 0;
    for (int w = 0; w < wave; ++w) wb += wsum[w];
    if (i < N_NODES) offs[i] = bbase[blockIdx.x] + wb + x - v;
}

// ---- pass 3: CSR fill via LDS cursors (no global atomics) ----
__global__ __launch_bounds__(256) void fill_kernel(
    const int* __restrict__ src, const int* __restrict__ dst,
    const int* __restrict__ offs, const int* __restrict__ pin,
    int* __restrict__ csr_src) {
    __shared__ int cur[RSIZE];
    int tid = threadIdx.x;
    int r = blockIdx.x % NRANGE;
    int c = blockIdx.x / NRANGE;
    int lo = r << RBITS;
    const int* pf = pin + ((size_t)(r * NCHUNK + c) << RBITS);
    for (int i = tid; i < RSIZE; i += 256) {
        int gi = lo + i;
        int o = (gi < N_NODES) ? offs[gi] : 0;
        cur[i] = o + pf[i];
    }
    __syncthreads();
    const int4* s4 = (const int4*)(src + c * CHUNK_E);
    const int4* d4 = (const int4*)(dst + c * CHUNK_E);
    for (int i = tid; i < CHUNK_E / 4; i += 256) {
        int4 s = s4[i];
        int4 d = d4[i];
        unsigned a;
        a = (unsigned)(d.x - lo); if (a < RSIZE) csr_src[atomicAdd(&cur[a], 1)] = s.x;
        a = (unsigned)(d.y - lo); if (a < RSIZE) csr_src[atomicAdd(&cur[a], 1)] = s.y;
        a = (unsigned)(d.z - lo); if (a < RSIZE) csr_src[atomicAdd(&cur[a], 1)] = s.z;
        a = (unsigned)(d.w - lo); if (a < RSIZE) csr_src[atomicAdd(&cur[a], 1)] = s.w;
    }
}

// ---- RNE fp32->bf16 pair pack ----
__device__ __forceinline__ unsigned bpack(float a, float b) {
    unsigned ua = __float_as_uint(a);
    unsigned ub = __float_as_uint(b);
    ua = (ua + 0x7FFFu + ((ua >> 16) & 1u)) >> 16;
    ub = (ub + 0x7FFFu + ((ub >> 16) & 1u)) >> 16;
    return ua | (ub << 16);
}

// ---- GEMM: h = bf16( (x @ W) * inv_sqrt(deg_out[row]) ) ----
// 64 rows/block, 256 threads, thread = 2 rows x 12 cols. LDS 60 KB -> 2 blocks/CU.
#define GR 64
__global__ __launch_bounds__(256) void gemm_kernel(
    const float* __restrict__ x, const float* __restrict__ W,
    const int* __restrict__ deg_out, unsigned* __restrict__ h, int nrows) {
    __shared__ float ws[96 * 96];    // 36 KB
    __shared__ float xT[96 * GR];    // 24 KB, xT[col][row]
    int tid = threadIdx.x;

    const float4* Wv = (const float4*)W;
    float4* wv = (float4*)ws;
    #pragma unroll
    for (int i = 0; i < 9; ++i) wv[tid + 256 * i] = Wv[tid + 256 * i];

    int r0 = blockIdx.x * GR;
    int nvalid = nrows - r0; if (nvalid > GR) nvalid = GR;
    const float4* xv = (const float4*)x;
    for (int i = tid; i < 24 * GR; i += 256) {
        int row = i & (GR - 1);
        int c4 = i >> 6;
        if (row < nvalid) {
            float4 v = xv[(size_t)(r0 + row) * 24 + c4];
            xT[(c4 * 4 + 0) * GR + row] = v.x;
            xT[(c4 * 4 + 1) * GR + row] = v.y;
            xT[(c4 * 4 + 2) * GR + row] = v.z;
            xT[(c4 * 4 + 3) * GR + row] = v.w;
        }
    }
    __syncthreads();

    int rg = tid >> 3;            // 0..31 -> rows rg*2, rg*2+1
    int cg = tid & 7;             // cols 12*cg .. 12*cg+11
    float4 a0[2], a1[2], a2[2];
    #pragma unroll
    for (int r = 0; r < 2; ++r) { a0[r] = {0,0,0,0}; a1[r] = {0,0,0,0}; a2[r] = {0,0,0,0}; }

    #pragma unroll 4
    for (int k = 0; k < 96; ++k) {
        float2 xs = *(const float2*)&xT[k * GR + rg * 2];
        float4 w0 = *(const float4*)&ws[k * 96 + 12 * cg];
        float4 w1 = *(const float4*)&ws[k * 96 + 12 * cg + 4];
        float4 w2 = *(const float4*)&ws[k * 96 + 12 * cg + 8];
        float xr[2] = {xs.x, xs.y};
        #pragma unroll
        for (int r = 0; r < 2; ++r) {
            a0[r].x += xr[r] * w0.x; a0[r].y += xr[r] * w0.y; a0[r].z += xr[r] * w0.z; a0[r].w += xr[r] * w0.w;
            a1[r].x += xr[r] * w1.x; a1[r].y += xr[r] * w1.y; a1[r].z += xr[r] * w1.z; a1[r].w += xr[r] * w1.w;
            a2[r].x += xr[r] * w2.x; a2[r].y += xr[r] * w2.y; a2[r].z += xr[r] * w2.z; a2[r].w += xr[r] * w2.w;
        }
    }

    #pragma unroll
    for (int r = 0; r < 2; ++r) {
        int row = r0 + rg * 2 + r;
        if (row < nrows) {
            int d = deg_out[row];
            float s = (d > 0) ? rsqrtf((float)d) : 0.f;
            unsigned* hp = h + (size_t)row * 48 + 6 * cg;
            uint2 p0, p1, p2;
            p0.x = bpack(a0[r].x * s, a0[r].y * s);
            p0.y = bpack(a0[r].z * s, a0[r].w * s);
            p1.x = bpack(a1[r].x * s, a1[r].y * s);
            p1.y = bpack(a1[r].z * s, a1[r].w * s);
            p2.x = bpack(a2[r].x * s, a2[r].y * s);
            p2.y = bpack(a2[r].z * s, a2[r].w * s);
            *(uint2*)(hp)     = p0;
            *(uint2*)(hp + 2) = p1;
            *(uint2*)(hp + 4) = p2;
        }
    }
}

// ---- aggregate: out[n] = inv_sqrt_in[n] * sum h[src_e] + b (bf16 gathers) ----
__device__ __forceinline__ void upadd(float* a, uint4 q) {
    a[0] += __uint_as_float(q.x << 16);
    a[1] += __uint_as_float(q.x & 0xffff0000u);
    a[2] += __uint_as_float(q.y << 16);
    a[3] += __uint_as_float(q.y & 0xffff0000u);
    a[4] += __uint_as_float(q.z << 16);
    a[5] += __uint_as_float(q.z & 0xffff0000u);
    a[6] += __uint_as_float(q.w << 16);
    a[7] += __uint_as_float(q.w & 0xffff0000u);
}

__global__ __launch_bounds__(256) void agg_kernel(
    const unsigned* __restrict__ h, const int* __restrict__ csr_src,
    const int* __restrict__ offs, const float* __restrict__ b,
    float* __restrict__ out, int nnodes) {
    int tid = threadIdx.x;
    int n = blockIdx.x * 64 + (tid >> 2);
    if (n >= nnodes) return;
    int j = tid & 3;                    // lane j owns uint4 slots j, j+4, j+8 of each row
    int start = offs[n], end = offs[n + 1];
    float acc[24];
    #pragma unroll
    for (int i = 0; i < 24; ++i) acc[i] = 0.f;
    const uint4* hb = (const uint4*)h;  // row = 12 uint4
    int e = start;
    for (; e + 2 <= end; e += 2) {
        size_t b0 = (size_t)csr_src[e] * 12 + j;
        size_t b1 = (size_t)csr_src[e + 1] * 12 + j;
        uint4 q0 = hb[b0], q1 = hb[b0 + 4], q2 = hb[b0 + 8];
        uint4 p0 = hb[b1], p1 = hb[b1 + 4], p2 = hb[b1 + 8];
        upadd(acc + 0, q0); upadd(acc + 8, q1); upadd(acc + 16, q2);
        upadd(acc + 0, p0); upadd(acc + 8, p1); upadd(acc + 16, p2);
    }
    if (e < end) {
        size_t b0 = (size_t)csr_src[e] * 12 + j;
        uint4 q0 = hb[b0], q1 = hb[b0 + 4], q2 = hb[b0 + 8];
        upadd(acc + 0, q0); upadd(acc + 8, q1); upadd(acc + 16, q2);
    }
    float inv = (end > start) ? rsqrtf((float)(end - start)) : 0.f;
    #pragma unroll
    for (int g = 0; g < 3; ++g) {
        int q = j + 4 * g;              // cols 8q .. 8q+7
        float4 bb0 = *(const float4*)(b + 8 * q);
        float4 bb1 = *(const float4*)(b + 8 * q + 4);
        float4 r0, r1;
        r0.x = acc[g * 8 + 0] * inv + bb0.x;
        r0.y = acc[g * 8 + 1] * inv + bb0.y;
        r0.z = acc[g * 8 + 2] * inv + bb0.z;
        r0.w = acc[g * 8 + 3] * inv + bb0.w;
        r1.x = acc[g * 8 + 4] * inv + bb1.x;
        r1.y = acc[g * 8 + 5] * inv + bb1.y;
        r1.z = acc[g * 8 + 6] * inv + bb1.z;
        r1.w = acc[g * 8 + 7] * inv + bb1.w;
        float4* o = (float4*)(out + (size_t)n * DFEAT + 8 * q);
        o[0] = r0; o[1] = r1;
    }
}

extern "C" void kernel_launch(void* const* d_in, const int* in_sizes, int n_in,
                              void* d_out, int out_size, void* d_ws, size_t ws_size,
                              hipStream_t stream) {
    const float* x  = (const float*)d_in[0];
    const float* W  = (const float*)d_in[1];
    const float* b  = (const float*)d_in[2];
    const int*   src = (const int*)d_in[3];
    const int*   dst = (const int*)d_in[4];
    float* out = (float*)d_out;

    // workspace layout
    int* deg_out = (int*)d_ws;                   // 50000
    int* deg_in  = deg_out + N_NODES;            // 50000
    int* offs    = deg_in + N_NODES;             // 50001
    int* csr_src = offs + N_NODES + 1;           // 800000
    int* bsum    = csr_src + N_EDGES;            // 196
    int* bbase   = bsum + 196;                   // 196
    size_t tbl_off = (((size_t)(2 * N_NODES + N_NODES + 1 + N_EDGES + 392)) * 4 + 255) & ~(size_t)255;
    int* pout = (int*)((char*)d_ws + tbl_off);               // 7*40*8192 = 2.29M ints
    int* pin  = pout + ((size_t)NRANGE * NCHUNK << RBITS);   // 2.29M ints
    // h (bf16, 50000*48 uints = 9.6 MB) aliases the pout table (dead after fill)
    unsigned* h = (unsigned*)pout;

    deg_hist_kernel<<<NRANGE * NCHUNK, 256, 0, stream>>>(src, dst, pout, pin);
    deg_reduce_kernel<<<(N_NODES + 255) / 256, 256, 0, stream>>>(pout, pin, deg_out, deg_in);

    int nb = (N_NODES + 255) / 256;  // 196
    scan_bsum_kernel<<<nb, 256, 0, stream>>>(deg_in, bsum);
    scan_base_kernel<<<1, 256, 0, stream>>>(bsum, bbase, offs, nb);
    scan_final_kernel<<<nb, 256, 0, stream>>>(deg_in, bbase, offs);

    fill_kernel<<<NRANGE * NCHUNK, 256, 0, stream>>>(src, dst, offs, pin, csr_src);

    gemm_kernel<<<(N_NODES + GR - 1) / GR, 256, 0, stream>>>(x, W, deg_out, h, N_NODES);

    agg_kernel<<<(N_NODES + 63) / 64, 256, 0, stream>>>(h, csr_src, offs, b, out, N_NODES);
}